// Round 1
// baseline (898.335 us; speedup 1.0000x reference)
//
#include <hip/hip_runtime.h>

// ScatterND add-reduction:  out = data.clone(); out[idx[k]] += updates[k]
// N=1048576, D=128, K=262144 (derived from in_sizes at launch).
//
// NO-WORKSPACE variant. Experiment: the baseline's timed window contains two
// ~341us / 2GiB fillBufferAligned dispatches (total 682us of 894us) that we
// believe are d_ws re-poison. This version never touches d_ws: the inverse
// map (N ints = 4 MiB) is stashed in the TAIL rows of `out` (last T = ceil(N/D)
// = 8192 rows), consumed by the fused pass over rows [0, N-T), and then the
// tail rows are finished with a plain copy + idx-driven RMW (no inv needed).
// Kernel-side HBM traffic is ~identical to baseline (~1.16 GiB).

// --- kernel 1: inv[i] = -1 for all N rows (vectorized int4) ----------------
__global__ void inv_init_kernel(int4* __restrict__ inv4, int n4) {
    int i = blockIdx.x * blockDim.x + threadIdx.x;
    if (i < n4) inv4[i] = make_int4(-1, -1, -1, -1);
}

// --- kernel 2: inv[idx[k]] = k  (indices unique, no atomics needed) --------
__global__ void inv_scatter_kernel(const int* __restrict__ idx,
                                   int* __restrict__ inv, int K) {
    int k = blockIdx.x * blockDim.x + threadIdx.x;
    if (k < K) inv[idx[k]] = k;
}

// --- kernel 3: fused copy+add over rows [0, rows_main). pow2 dvec path. ----
__global__ void fused_scatter_add_kernel(const float4* __restrict__ data,
                                         const float4* __restrict__ upd,
                                         const int* __restrict__ inv,
                                         float4* __restrict__ out,
                                         int nvec_main, unsigned shift,
                                         unsigned lanemask) {
    int i = blockIdx.x * blockDim.x + threadIdx.x;
    if (i >= nvec_main) return;
    unsigned row  = (unsigned)i >> shift;
    unsigned lane = (unsigned)i & lanemask;
    float4 v = data[i];
    int k = inv[row];
    if (k >= 0) {
        float4 u = upd[((long long)k << shift) + lane];
        v.x += u.x; v.y += u.y; v.z += u.z; v.w += u.w;
    }
    out[i] = v;
}

// --- kernel 3b: same, generic division (non-pow2 dvec safety net) ----------
__global__ void fused_scatter_add_div_kernel(const float4* __restrict__ data,
                                             const float4* __restrict__ upd,
                                             const int* __restrict__ inv,
                                             float4* __restrict__ out,
                                             int nvec_main, unsigned dvec) {
    int i = blockIdx.x * blockDim.x + threadIdx.x;
    if (i >= nvec_main) return;
    unsigned row  = (unsigned)i / dvec;
    unsigned lane = (unsigned)i - row * dvec;
    float4 v = data[i];
    int k = inv[row];
    if (k >= 0) {
        float4 u = upd[(long long)k * dvec + lane];
        v.x += u.x; v.y += u.y; v.z += u.z; v.w += u.w;
    }
    out[i] = v;
}

// --- kernel 4: plain copy (tail rows; overwrites the inv stash) ------------
__global__ void copy_kernel(const float4* __restrict__ src,
                            float4* __restrict__ dst, int nvec) {
    int i = blockIdx.x * blockDim.x + threadIdx.x;
    if (i < nvec) dst[i] = src[i];
}

// --- kernel 5: idx-driven RMW for tail rows only (expected ~K*T/N hits) ----
__global__ void tail_rmw_kernel(const float4* __restrict__ upd,
                                const int* __restrict__ idx,
                                float4* __restrict__ out,
                                int K, int row_lo, unsigned dvec) {
    int k = blockIdx.x * blockDim.x + threadIdx.x;
    if (k >= K) return;
    int r = idx[k];
    if (r < row_lo) return;
    const float4* u = upd + (long long)k * dvec;
    float4*       o = out + (long long)r * dvec;
    for (unsigned j = 0; j < dvec; ++j) {
        float4 v = o[j];
        float4 uu = u[j];
        v.x += uu.x; v.y += uu.y; v.z += uu.z; v.w += uu.w;
        o[j] = v;
    }
}

extern "C" void kernel_launch(void* const* d_in, const int* in_sizes, int n_in,
                              void* d_out, int out_size, void* d_ws, size_t ws_size,
                              hipStream_t stream) {
    const float* data = (const float*)d_in[0];
    const int*   idx  = (const int*)d_in[1];
    const float* upd  = (const float*)d_in[2];
    float* out = (float*)d_out;

    const int K = in_sizes[1];                 // 262144
    const int D = in_sizes[2] / K;             // 128
    const int N = in_sizes[0] / D;             // 1048576
    const unsigned dvec = (unsigned)(D / 4);   // 32 float4 per row

    const int BS = 256;

    // Tail rows that will temporarily hold the inverse map (N ints).
    const int T         = (N + D - 1) / D;     // 8192 rows (4 MiB >= N ints)
    const int rows_main = N - T;               // rows served by the fused pass
    const int nvec_main = rows_main * (int)dvec;
    const int tvec      = T * (int)dvec;       // tail float4 count

    // inv stash lives in the tail rows of `out` (never touches d_ws).
    int* inv = (int*)out + (long long)rows_main * D;

    // 1) init inv = -1 (N ints, N % 4 == 0 here)
    int n4 = (N + 3) / 4;
    inv_init_kernel<<<(n4 + BS - 1) / BS, BS, 0, stream>>>((int4*)inv, n4);

    // 2) inv[idx[k]] = k
    inv_scatter_kernel<<<(K + BS - 1) / BS, BS, 0, stream>>>(idx, inv, K);

    // 3) fused streaming pass over rows [0, rows_main)
    bool pow2 = (dvec & (dvec - 1)) == 0;
    if (pow2) {
        unsigned shift = 0;
        while ((1u << shift) < dvec) ++shift;
        fused_scatter_add_kernel<<<(nvec_main + BS - 1) / BS, BS, 0, stream>>>(
            (const float4*)data, (const float4*)upd, inv, (float4*)out,
            nvec_main, shift, dvec - 1);
    } else {
        fused_scatter_add_div_kernel<<<(nvec_main + BS - 1) / BS, BS, 0, stream>>>(
            (const float4*)data, (const float4*)upd, inv, (float4*)out,
            nvec_main, dvec);
    }

    // 4) tail copy: out[r] = data[r] for r in [rows_main, N). Overwrites inv
    //    stash (fused pass is already done with it; same-stream ordering).
    copy_kernel<<<(tvec + BS - 1) / BS, BS, 0, stream>>>(
        (const float4*)data + (long long)rows_main * dvec,
        (float4*)out + (long long)rows_main * dvec, tvec);

    // 5) tail RMW: updates targeting tail rows (idx-driven, no inv needed)
    tail_rmw_kernel<<<(K + BS - 1) / BS, BS, 0, stream>>>(
        (const float4*)upd, idx, (float4*)out, K, rows_main, dvec);
}